// Round 1
// baseline (1889.508 us; speedup 1.0000x reference)
//
#include <hip/hip_runtime.h>
#include <hip/hip_bf16.h>
#include <math.h>

#define D_MODEL 1024
#define NHEAD 16
#define DK 64
#define SEQ 2048
#define NBATCH 2
#define MROWS (NBATCH * SEQ)   // 4096

// ---------------- GEMM config: Y[m,n] = sum_k A[m,k] * W[n,k] ----------------
#define BM 64
#define BN 64
#define BK 16

// QKV projection + RoPE epilogue. gridDim.z selects {q,k,v}.
// Output layout: (B, H, S, DK)
__global__ __launch_bounds__(256) void qkv_rope_gemm(
    const float* __restrict__ x,
    const float* __restrict__ Wq, const float* __restrict__ Wk, const float* __restrict__ Wv,
    float* __restrict__ q_ws, float* __restrict__ k_ws, float* __restrict__ v_ws)
{
    const int which = blockIdx.z;
    const float* W = (which == 0) ? Wq : (which == 1) ? Wk : Wv;
    float* outp    = (which == 0) ? q_ws : (which == 1) ? k_ws : v_ws;

    __shared__ float As[BK][BM + 4];
    __shared__ float Bs[BK][BN + 4];

    const int tid = threadIdx.x;
    const int m0 = blockIdx.x * BM;
    const int n0 = blockIdx.y * BN;
    const int ty = tid >> 4, tx = tid & 15;   // 16x16 threads, 4x4 micro-tile
    const int lm = tid >> 2;                  // staging: row within tile
    const int lk = (tid & 3) << 2;            // staging: k offset (float4)

    float acc[4][4] = {};

    for (int k0 = 0; k0 < D_MODEL; k0 += BK) {
        float4 av = *(const float4*)&x[(size_t)(m0 + lm) * D_MODEL + k0 + lk];
        float4 bv = *(const float4*)&W[(size_t)(n0 + lm) * D_MODEL + k0 + lk];
        __syncthreads();
        As[lk + 0][lm] = av.x; As[lk + 1][lm] = av.y; As[lk + 2][lm] = av.z; As[lk + 3][lm] = av.w;
        Bs[lk + 0][lm] = bv.x; Bs[lk + 1][lm] = bv.y; Bs[lk + 2][lm] = bv.z; Bs[lk + 3][lm] = bv.w;
        __syncthreads();
#pragma unroll
        for (int kk = 0; kk < BK; ++kk) {
            float4 a4 = *(const float4*)&As[kk][ty << 2];
            float4 b4 = *(const float4*)&Bs[kk][tx << 2];
            float ar[4] = {a4.x, a4.y, a4.z, a4.w};
            float br[4] = {b4.x, b4.y, b4.z, b4.w};
#pragma unroll
            for (int i = 0; i < 4; ++i)
#pragma unroll
                for (int jj = 0; jj < 4; ++jj)
                    acc[i][jj] += ar[i] * br[jj];
        }
    }

    const int nbase = n0 + (tx << 2);
    const int h = nbase >> 6;
    const int dbase = nbase & 63;             // multiple of 4 -> pairs (d,d+1),(d+2,d+3)
    const float ln_theta = 9.210340371976184f; // ln(10000)
#pragma unroll
    for (int i = 0; i < 4; ++i) {
        int m = m0 + (ty << 2) + i;
        int b = m >> 11;            // / SEQ
        int s = m & (SEQ - 1);
        float o0 = acc[i][0], o1 = acc[i][1], o2 = acc[i][2], o3 = acc[i][3];
        if (which < 2) {
            float inv0 = expf(-ln_theta * (float)(dbase)     * (1.0f / 64.0f));
            float inv1 = expf(-ln_theta * (float)(dbase + 2) * (1.0f / 64.0f));
            float s0, c0, s1, c1;
            sincosf((float)s * inv0, &s0, &c0);
            sincosf((float)s * inv1, &s1, &c1);
            float e0 = o0 * c0 - o1 * s0;
            float e1 = o0 * s0 + o1 * c0;
            float e2 = o2 * c1 - o3 * s1;
            float e3 = o2 * s1 + o3 * c1;
            o0 = e0; o1 = e1; o2 = e2; o3 = e3;
        }
        float* dst = outp + (((size_t)b * NHEAD + h) * SEQ + s) * DK + dbase;
        *(float4*)dst = make_float4(o0, o1, o2, o3);
    }
}

// Plain GEMM: out[m,n] = sum_k A[m,k] * W[n,k]
__global__ __launch_bounds__(256) void proj_gemm(
    const float* __restrict__ A, const float* __restrict__ W, float* __restrict__ out)
{
    __shared__ float As[BK][BM + 4];
    __shared__ float Bs[BK][BN + 4];

    const int tid = threadIdx.x;
    const int m0 = blockIdx.x * BM;
    const int n0 = blockIdx.y * BN;
    const int ty = tid >> 4, tx = tid & 15;
    const int lm = tid >> 2;
    const int lk = (tid & 3) << 2;

    float acc[4][4] = {};

    for (int k0 = 0; k0 < D_MODEL; k0 += BK) {
        float4 av = *(const float4*)&A[(size_t)(m0 + lm) * D_MODEL + k0 + lk];
        float4 bv = *(const float4*)&W[(size_t)(n0 + lm) * D_MODEL + k0 + lk];
        __syncthreads();
        As[lk + 0][lm] = av.x; As[lk + 1][lm] = av.y; As[lk + 2][lm] = av.z; As[lk + 3][lm] = av.w;
        Bs[lk + 0][lm] = bv.x; Bs[lk + 1][lm] = bv.y; Bs[lk + 2][lm] = bv.z; Bs[lk + 3][lm] = bv.w;
        __syncthreads();
#pragma unroll
        for (int kk = 0; kk < BK; ++kk) {
            float4 a4 = *(const float4*)&As[kk][ty << 2];
            float4 b4 = *(const float4*)&Bs[kk][tx << 2];
            float ar[4] = {a4.x, a4.y, a4.z, a4.w};
            float br[4] = {b4.x, b4.y, b4.z, b4.w};
#pragma unroll
            for (int i = 0; i < 4; ++i)
#pragma unroll
                for (int jj = 0; jj < 4; ++jj)
                    acc[i][jj] += ar[i] * br[jj];
        }
    }

#pragma unroll
    for (int i = 0; i < 4; ++i) {
        int m = m0 + (ty << 2) + i;
        *(float4*)&out[(size_t)m * D_MODEL + n0 + (tx << 2)] =
            make_float4(acc[i][0], acc[i][1], acc[i][2], acc[i][3]);
    }
}

// Flash attention, causal. Block = 256 threads = one 64-row Q tile for one (b,h).
// q/k/v layout (B,H,S,DK); output written to attn_ws in (B,S,D) layout.
__global__ __launch_bounds__(256) void flash_attn(
    const float* __restrict__ q_ws, const float* __restrict__ k_ws,
    const float* __restrict__ v_ws, float* __restrict__ attn_ws)
{
    const int qt = blockIdx.x, h = blockIdx.y, b = blockIdx.z;
    const int bh = b * NHEAD + h;
    const int qbase = qt << 6;

    __shared__ float Ks[64][68];
    __shared__ float Vs[64][68];
    __shared__ float Ss[64][68];
    __shared__ float rowscale[64];
    __shared__ float rowl[64];

    const int tid = threadIdx.x;
    const int r = tid & 63;     // my q row
    const int j = tid >> 6;     // 0..3: my 16-col score slice / 16-dim output slice
    const int d0 = j << 4;

    // Q row in registers (4-way redundant global read, L2-resident)
    const float* qrow = q_ws + ((size_t)bh * SEQ + qbase + r) * DK;
    float4 qreg[16];
#pragma unroll
    for (int d4 = 0; d4 < 16; ++d4) qreg[d4] = *(const float4*)&qrow[d4 << 2];

    float o[16] = {};
    float mrun = -1e30f, lrun = 0.f;

    const float* kbp = k_ws + (size_t)bh * SEQ * DK;
    const float* vbp = v_ws + (size_t)bh * SEQ * DK;

    for (int kt = 0; kt <= qt; ++kt) {
        const int kc = kt << 6;
        const float* kp = kbp + (size_t)kc * DK;
        const float* vp = vbp + (size_t)kc * DK;
        __syncthreads();   // previous iteration fully consumed
#pragma unroll
        for (int i = 0; i < 4; ++i) {
            int off = (i << 10) + (tid << 2);
            int c = off >> 6, d = off & 63;
            *(float4*)&Ks[c][d] = *(const float4*)&kp[off];
            *(float4*)&Vs[c][d] = *(const float4*)&vp[off];
        }
        __syncthreads();

        // ---- scores: rows r, cols d0..d0+15 ----
        float sacc[16];
        const int qpos = qbase + r;
#pragma unroll
        for (int c16 = 0; c16 < 16; ++c16) {
            int c = d0 + c16;
            float a = 0.f;
#pragma unroll
            for (int d4 = 0; d4 < 16; ++d4) {
                float4 k4 = *(const float4*)&Ks[c][d4 << 2];
                float4 q4 = qreg[d4];
                a += q4.x * k4.x + q4.y * k4.y + q4.z * k4.z + q4.w * k4.w;
            }
            sacc[c16] = (kc + c <= qpos) ? a * 0.125f : -1e30f;
        }
#pragma unroll
        for (int c16 = 0; c16 < 16; c16 += 4)
            *(float4*)&Ss[r][d0 + c16] =
                make_float4(sacc[c16], sacc[c16 + 1], sacc[c16 + 2], sacc[c16 + 3]);
        __syncthreads();

        // ---- online softmax: one thread per row (wave 0) ----
        if (tid < 64) {
            float tm = -1e30f;
#pragma unroll
            for (int c = 0; c < 64; c += 4) {
                float4 sv = *(const float4*)&Ss[tid][c];
                tm = fmaxf(tm, fmaxf(fmaxf(sv.x, sv.y), fmaxf(sv.z, sv.w)));
            }
            float newm = fmaxf(mrun, tm);
            float esc = expf(mrun - newm);
            float psum = 0.f;
#pragma unroll
            for (int c = 0; c < 64; c += 4) {
                float4 sv = *(const float4*)&Ss[tid][c];
                sv.x = expf(sv.x - newm); sv.y = expf(sv.y - newm);
                sv.z = expf(sv.z - newm); sv.w = expf(sv.w - newm);
                psum += sv.x + sv.y + sv.z + sv.w;
                *(float4*)&Ss[tid][c] = sv;
            }
            lrun = lrun * esc + psum;
            mrun = newm;
            rowscale[tid] = esc;
        }
        __syncthreads();

        // ---- PV: o[d0..d0+15] for row r ----
        const float esc = rowscale[r];
#pragma unroll
        for (int dd = 0; dd < 16; ++dd) o[dd] *= esc;
#pragma unroll
        for (int cq = 0; cq < 4; ++cq) {
            float4 p4[4];
#pragma unroll
            for (int t = 0; t < 4; ++t) p4[t] = *(const float4*)&Ss[r][(cq << 4) + (t << 2)];
            const float* pp = (const float*)p4;
#pragma unroll
            for (int ci = 0; ci < 16; ++ci) {
                int c = (cq << 4) + ci;
                float p = pp[ci];
                float4 v0 = *(const float4*)&Vs[c][d0 + 0];
                float4 v1 = *(const float4*)&Vs[c][d0 + 4];
                float4 v2 = *(const float4*)&Vs[c][d0 + 8];
                float4 v3 = *(const float4*)&Vs[c][d0 + 12];
                o[0]  += p * v0.x; o[1]  += p * v0.y; o[2]  += p * v0.z; o[3]  += p * v0.w;
                o[4]  += p * v1.x; o[5]  += p * v1.y; o[6]  += p * v1.z; o[7]  += p * v1.w;
                o[8]  += p * v2.x; o[9]  += p * v2.y; o[10] += p * v2.z; o[11] += p * v2.w;
                o[12] += p * v3.x; o[13] += p * v3.y; o[14] += p * v3.z; o[15] += p * v3.w;
            }
        }
    }

    if (tid < 64) rowl[tid] = lrun;
    __syncthreads();
    const float invl = 1.0f / rowl[r];
    float* op = attn_ws + ((size_t)b * SEQ + qbase + r) * D_MODEL + h * DK + d0;
#pragma unroll
    for (int dd = 0; dd < 16; dd += 4)
        *(float4*)&op[dd] = make_float4(o[dd] * invl, o[dd + 1] * invl,
                                        o[dd + 2] * invl, o[dd + 3] * invl);
}

extern "C" void kernel_launch(void* const* d_in, const int* in_sizes, int n_in,
                              void* d_out, int out_size, void* d_ws, size_t ws_size,
                              hipStream_t stream) {
    const float* x  = (const float*)d_in[0];
    const float* Wq = (const float*)d_in[1];
    const float* Wk = (const float*)d_in[2];
    const float* Wv = (const float*)d_in[3];
    const float* Wo = (const float*)d_in[4];
    float* out = (float*)d_out;

    const size_t qkv_elems = (size_t)NBATCH * NHEAD * SEQ * DK; // 4,194,304
    float* q_ws    = (float*)d_ws;
    float* k_ws    = q_ws + qkv_elems;
    float* v_ws    = k_ws + qkv_elems;
    float* attn_ws = v_ws + qkv_elems;   // total 64 MB fp32

    dim3 blk(256);
    qkv_rope_gemm<<<dim3(MROWS / BM, D_MODEL / BN, 3), blk, 0, stream>>>(
        x, Wq, Wk, Wv, q_ws, k_ws, v_ws);
    flash_attn<<<dim3(SEQ / 64, NHEAD, NBATCH), blk, 0, stream>>>(
        q_ws, k_ws, v_ws, attn_ws);
    proj_gemm<<<dim3(MROWS / BM, D_MODEL / BN, 1), blk, 0, stream>>>(
        attn_ws, Wo, out);
}

// Round 2
// 268.579 us; speedup vs baseline: 7.0352x; 7.0352x over previous
//
#include <hip/hip_runtime.h>

#define D_MODEL 1024
#define NHEAD 16
#define DK 64
#define SEQ 2048
#define NBATCH 2
#define MROWS (NBATCH * SEQ)   // 4096

typedef unsigned short u16;
typedef short bf16x8 __attribute__((ext_vector_type(8)));   // 8 bf16 = 4 VGPR
typedef float f32x4 __attribute__((ext_vector_type(4)));
typedef unsigned short u16x8 __attribute__((ext_vector_type(8)));

__device__ __forceinline__ u16 f2bf(float f) {
    union { float f; unsigned u; } v; v.f = f;
    unsigned r = v.u + 0x7FFFu + ((v.u >> 16) & 1u);   // RNE
    return (u16)(r >> 16);
}

__device__ __forceinline__ void gload16(const void* g, void* s) {
    __builtin_amdgcn_global_load_lds((const __attribute__((address_space(1))) void*)g,
                                     (__attribute__((address_space(3))) void*)s, 16, 0, 0);
}

// ---------------- fp32 -> bf16 conversion (x, Wq|Wk|Wv stacked, Wo) ----------------
#define XN 4194304   // 4096*1024
#define WN 1048576   // 1024*1024

__global__ __launch_bounds__(256) void convert_bf16(
    const float* __restrict__ x, const float* __restrict__ wq, const float* __restrict__ wk,
    const float* __restrict__ wv, const float* __restrict__ wo,
    u16* __restrict__ xb, u16* __restrict__ wqkv, u16* __restrict__ wob)
{
    size_t base = ((size_t)blockIdx.x * 256 + threadIdx.x) * 8;
    const float* src; u16* dst;
    if (base < XN)               { src = x  + base;                dst = xb   + base; }
    else if (base < XN + WN)     { src = wq + (base - XN);         dst = wqkv + (base - XN); }
    else if (base < XN + 2*WN)   { src = wk + (base - XN - WN);    dst = wqkv + (base - XN); }
    else if (base < XN + 3*WN)   { src = wv + (base - XN - 2*WN);  dst = wqkv + (base - XN); }
    else                         { src = wo + (base - XN - 3*WN);  dst = wob  + (base - XN - 3*WN); }
    float4 a = *(const float4*)&src[0];
    float4 b = *(const float4*)&src[4];
    u16x8 o;
    o[0] = f2bf(a.x); o[1] = f2bf(a.y); o[2] = f2bf(a.z); o[3] = f2bf(a.w);
    o[4] = f2bf(b.x); o[5] = f2bf(b.y); o[6] = f2bf(b.z); o[7] = f2bf(b.w);
    *(u16x8*)dst = o;
}

// ---------------- QKV GEMM (M=4096, N=3072, K=1024) + RoPE epilogue ----------------
// q,k out: (B,H,S,DK) bf16, q scaled by 0.125.  v out: (B,H,DK,S) bf16 (transposed).
__global__ __launch_bounds__(256) void gemm_qkv(
    const u16* __restrict__ A, const u16* __restrict__ B,
    u16* __restrict__ qo, u16* __restrict__ ko, u16* __restrict__ vo)
{
    __shared__ __align__(16) u16 sbuf[17408];   // As(4096) + Bs(4096); epilogue scratch 4*64*68
    u16* As = sbuf;
    u16* Bs = sbuf + 4096;

    const int tid = threadIdx.x, w = tid >> 6, l = tid & 63;
    const int l15 = l & 15, lg = l >> 4;
    const int m0 = blockIdx.x * 128, n0 = blockIdx.y * 128;
    const int wm = (w >> 1) * 64, wn = (w & 1) * 64;

    f32x4 zero = {0.f, 0.f, 0.f, 0.f};
    f32x4 acc[4][4];
#pragma unroll
    for (int i = 0; i < 4; ++i)
#pragma unroll
        for (int j = 0; j < 4; ++j) acc[i][j] = zero;

    for (int k0 = 0; k0 < D_MODEL; k0 += 32) {
        __syncthreads();
#pragma unroll
        for (int it = 0; it < 2; ++it) {
            int ubase = it * 256 + w * 64;
            int u = ubase + l, row = u >> 2, kq = u & 3;
            gload16(A + (size_t)(m0 + row) * D_MODEL + k0 + kq * 8, &As[ubase * 8]);
        }
#pragma unroll
        for (int it = 0; it < 2; ++it) {
            int ubase = it * 256 + w * 64;
            int u = ubase + l, row = u >> 2, kq = u & 3;
            gload16(B + (size_t)(n0 + row) * D_MODEL + k0 + kq * 8, &Bs[ubase * 8]);
        }
        __syncthreads();
        bf16x8 af[4], bf[4];
#pragma unroll
        for (int mi = 0; mi < 4; ++mi) af[mi] = *(const bf16x8*)&As[(wm + mi * 16 + l15) * 32 + lg * 8];
#pragma unroll
        for (int ni = 0; ni < 4; ++ni) bf[ni] = *(const bf16x8*)&Bs[(wn + ni * 16 + l15) * 32 + lg * 8];
#pragma unroll
        for (int mi = 0; mi < 4; ++mi)
#pragma unroll
            for (int ni = 0; ni < 4; ++ni)
                acc[mi][ni] = __builtin_amdgcn_mfma_f32_16x16x32_bf16(af[mi], bf[ni], acc[mi][ni], 0, 0, 0);
    }

    const int which = n0 >> 10;   // 0=q 1=k 2=v (block-uniform)
    if (which < 2) {
        u16* outp = (which == 0) ? qo : ko;
        const float lnth = 9.210340371976184f;   // ln(10000)
#pragma unroll
        for (int ni = 0; ni < 4; ++ni) {
            int n = n0 + wn + ni * 16 + l15;
            int hh = (n >> 6) & 15, d = n & 63;
            float invf = __expf(-lnth * (float)(d & 62) * (1.0f / 64.0f));
            float sgn = (d & 1) ? 1.0f : -1.0f;
#pragma unroll
            for (int mi = 0; mi < 4; ++mi) {
#pragma unroll
                for (int i = 0; i < 4; ++i) {
                    int m = m0 + wm + mi * 16 + lg * 4 + i;
                    int bb = m >> 11, s = m & (SEQ - 1);
                    float v = acc[mi][ni][i];
                    float pv = __shfl_xor(v, 1);
                    float sn, cs;
                    __sincosf((float)s * invf, &sn, &cs);
                    float res = v * cs + sgn * pv * sn;
                    if (which == 0) res *= 0.125f;   // 1/sqrt(dk), exact
                    outp[((size_t)(bb * NHEAD + hh) * SEQ + s) * DK + d] = f2bf(res);
                }
            }
        }
    } else {
        // V: per-wave LDS transpose, write (B,H,DK,S)
        __syncthreads();   // As/Bs dead
        u16* sc = &sbuf[w * 64 * 68];
#pragma unroll
        for (int mi = 0; mi < 4; ++mi)
#pragma unroll
            for (int ni = 0; ni < 4; ++ni)
#pragma unroll
                for (int i = 0; i < 4; ++i)
                    sc[(mi * 16 + lg * 4 + i) * 68 + ni * 16 + l15] = f2bf(acc[mi][ni][i]);
        int vcol = n0 - 2048 + wn;          // multiple of 64
        int hh = vcol >> 6;
        int m = m0 + wm, bb = m >> 11, s0 = m & (SEQ - 1);
        u16* dst = vo + ((size_t)(bb * NHEAD + hh) * DK + l) * SEQ + s0;
#pragma unroll
        for (int j8 = 0; j8 < 8; ++j8) {
            u16x8 val;
#pragma unroll
            for (int jj = 0; jj < 8; ++jj) val[jj] = sc[(j8 * 8 + jj) * 68 + l];
            *(u16x8*)&dst[j8 * 8] = val;
        }
    }
}

// ---------------- Flash attention, causal, bf16 MFMA ----------------
// 4 waves x 16 q-rows; K tile 64x64 [s][d], Vt tile 64x64 [d][s], both XOR-swizzled.
__global__ __launch_bounds__(256) void attn_mfma(
    const u16* __restrict__ qb, const u16* __restrict__ kb,
    const u16* __restrict__ vtb, u16* __restrict__ attnb)
{
    __shared__ __align__(16) u16 Ks[4096];
    __shared__ __align__(16) u16 Vt[4096];
    __shared__ __align__(16) u16 Qs[4096];   // reused as per-wave P scratch after Q-frag reads

    const int qt = (SEQ / 64 - 1) - blockIdx.x;   // long blocks first
    const int h = blockIdx.y, b = blockIdx.z;
    const int bh = b * NHEAD + h;
    const int qbase = qt * 64;
    const int tid = threadIdx.x, w = tid >> 6, l = tid & 63;
    const int l15 = l & 15, lg = l >> 4;

    // stage Q (swizzled via pre-swizzled global source)
    const u16* qsrc = qb + ((size_t)bh * SEQ + qbase) * DK;
#pragma unroll
    for (int it = 0; it < 2; ++it) {
        int ubase = it * 256 + w * 64;
        int u = ubase + l, row = u >> 3, cq = u & 7;
        gload16(qsrc + row * 64 + ((cq ^ (row & 7)) * 8), &Qs[ubase * 8]);
    }
    __syncthreads();
    bf16x8 aq[2];
#pragma unroll
    for (int kk = 0; kk < 2; ++kk) {
        int row = w * 16 + l15;
        int cq = kk * 4 + lg;
        aq[kk] = *(const bf16x8*)&Qs[(row * 8 + (cq ^ (row & 7))) * 8];
    }

    f32x4 zero = {0.f, 0.f, 0.f, 0.f};
    f32x4 of[4];
#pragma unroll
    for (int i = 0; i < 4; ++i) of[i] = zero;
    float mrun[4] = {-1e30f, -1e30f, -1e30f, -1e30f};
    float lrun[4] = {0.f, 0.f, 0.f, 0.f};

    const u16* kg = kb + (size_t)bh * SEQ * DK;
    const u16* vg = vtb + (size_t)bh * DK * SEQ;
    u16* Ps = &Qs[w * 1024];   // 16 rows x 64 cols, this wave's own Q rows

    for (int kt = 0; kt <= qt; ++kt) {
        const int kc = kt * 64;
        __syncthreads();
#pragma unroll
        for (int it = 0; it < 2; ++it) {
            int ubase = it * 256 + w * 64;
            int u = ubase + l, row = u >> 3, cq = u & 7;
            gload16(kg + (size_t)(kc + row) * DK + ((cq ^ (row & 7)) * 8), &Ks[ubase * 8]);
            gload16(vg + (size_t)row * SEQ + kc + ((cq ^ (row & 7)) * 8), &Vt[ubase * 8]);
        }
        __syncthreads();

        // QK^T: S[16q][64k]
        f32x4 s4[4];
#pragma unroll
        for (int ni = 0; ni < 4; ++ni) {
            s4[ni] = zero;
#pragma unroll
            for (int kk = 0; kk < 2; ++kk) {
                int row = ni * 16 + l15;
                int cq = kk * 4 + lg;
                bf16x8 bk = *(const bf16x8*)&Ks[(row * 8 + (cq ^ (row & 7))) * 8];
                s4[ni] = __builtin_amdgcn_mfma_f32_16x16x32_bf16(aq[kk], bk, s4[ni], 0, 0, 0);
            }
        }
        if (kt == qt) {   // diagonal tile mask
#pragma unroll
            for (int ni = 0; ni < 4; ++ni)
#pragma unroll
                for (int i = 0; i < 4; ++i)
                    if (ni * 16 + l15 > w * 16 + lg * 4 + i) s4[ni][i] = -1e30f;
        }

        // online softmax (rows live across 16 lanes of same lg group)
        float tmax[4], scl[4], rsum[4];
#pragma unroll
        for (int i = 0; i < 4; ++i) {
            float t = fmaxf(fmaxf(s4[0][i], s4[1][i]), fmaxf(s4[2][i], s4[3][i]));
#pragma unroll
            for (int msk = 1; msk < 16; msk <<= 1) t = fmaxf(t, __shfl_xor(t, msk));
            float mn = fmaxf(mrun[i], t);
            scl[i] = __expf(mrun[i] - mn);
            mrun[i] = mn;
            rsum[i] = 0.f;
        }
#pragma unroll
        for (int ni = 0; ni < 4; ++ni)
#pragma unroll
            for (int i = 0; i < 4; ++i) {
                float p = __expf(s4[ni][i] - mrun[i]);
                rsum[i] += p;
                int q = lg * 4 + i;
                int colb = ni * 32 + l15 * 2;
                Ps[q * 64 + ((colb ^ ((q & 7) << 4)) >> 1)] = f2bf(p);
            }
#pragma unroll
        for (int i = 0; i < 4; ++i) {
#pragma unroll
            for (int msk = 1; msk < 16; msk <<= 1) rsum[i] += __shfl_xor(rsum[i], msk);
            lrun[i] = lrun[i] * scl[i] + rsum[i];
        }
        // rescale O
#pragma unroll
        for (int n2 = 0; n2 < 4; ++n2)
#pragma unroll
            for (int i = 0; i < 4; ++i) of[n2][i] *= scl[i];

        // P fragments (A-layout) from own Ps region
        bf16x8 ap[2];
#pragma unroll
        for (int kk = 0; kk < 2; ++kk) {
            int q = l15;
            int c = kk * 64 + lg * 16;
            int cb = c ^ ((q & 7) << 4);
            ap[kk] = *(const bf16x8*)&Ps[q * 64 + (cb >> 1)];
        }
        // PV: O[16q][64d]
#pragma unroll
        for (int n2 = 0; n2 < 4; ++n2)
#pragma unroll
            for (int kk = 0; kk < 2; ++kk) {
                int row = n2 * 16 + l15;
                int cq = kk * 4 + lg;
                bf16x8 bv = *(const bf16x8*)&Vt[(row * 8 + (cq ^ (row & 7))) * 8];
                of[n2] = __builtin_amdgcn_mfma_f32_16x16x32_bf16(ap[kk], bv, of[n2], 0, 0, 0);
            }
    }

    // epilogue: O/l -> attn (B,S,D) bf16
#pragma unroll
    for (int n2 = 0; n2 < 4; ++n2)
#pragma unroll
        for (int i = 0; i < 4; ++i) {
            int qrow = qbase + w * 16 + lg * 4 + i;
            int d = n2 * 16 + l15;
            float res = of[n2][i] / lrun[i];
            attnb[((size_t)(b * SEQ + qrow)) * D_MODEL + h * DK + d] = f2bf(res);
        }
}

// ---------------- Output projection GEMM (M=4096, N=1024, K=1024), fp32 out ----------------
__global__ __launch_bounds__(256) void gemm_proj(
    const u16* __restrict__ A, const u16* __restrict__ B, float* __restrict__ out)
{
    __shared__ __align__(16) u16 sbuf[8192];
    u16* As = sbuf;
    u16* Bs = sbuf + 4096;

    const int tid = threadIdx.x, w = tid >> 6, l = tid & 63;
    const int l15 = l & 15, lg = l >> 4;
    const int m0 = blockIdx.x * 128, n0 = blockIdx.y * 128;
    const int wm = (w >> 1) * 64, wn = (w & 1) * 64;

    f32x4 zero = {0.f, 0.f, 0.f, 0.f};
    f32x4 acc[4][4];
#pragma unroll
    for (int i = 0; i < 4; ++i)
#pragma unroll
        for (int j = 0; j < 4; ++j) acc[i][j] = zero;

    for (int k0 = 0; k0 < D_MODEL; k0 += 32) {
        __syncthreads();
#pragma unroll
        for (int it = 0; it < 2; ++it) {
            int ubase = it * 256 + w * 64;
            int u = ubase + l, row = u >> 2, kq = u & 3;
            gload16(A + (size_t)(m0 + row) * D_MODEL + k0 + kq * 8, &As[ubase * 8]);
        }
#pragma unroll
        for (int it = 0; it < 2; ++it) {
            int ubase = it * 256 + w * 64;
            int u = ubase + l, row = u >> 2, kq = u & 3;
            gload16(B + (size_t)(n0 + row) * D_MODEL + k0 + kq * 8, &Bs[ubase * 8]);
        }
        __syncthreads();
        bf16x8 af[4], bf[4];
#pragma unroll
        for (int mi = 0; mi < 4; ++mi) af[mi] = *(const bf16x8*)&As[(wm + mi * 16 + l15) * 32 + lg * 8];
#pragma unroll
        for (int ni = 0; ni < 4; ++ni) bf[ni] = *(const bf16x8*)&Bs[(wn + ni * 16 + l15) * 32 + lg * 8];
#pragma unroll
        for (int mi = 0; mi < 4; ++mi)
#pragma unroll
            for (int ni = 0; ni < 4; ++ni)
                acc[mi][ni] = __builtin_amdgcn_mfma_f32_16x16x32_bf16(af[mi], bf[ni], acc[mi][ni], 0, 0, 0);
    }

#pragma unroll
    for (int mi = 0; mi < 4; ++mi)
#pragma unroll
        for (int ni = 0; ni < 4; ++ni)
#pragma unroll
            for (int i = 0; i < 4; ++i) {
                int m = m0 + wm + mi * 16 + lg * 4 + i;
                int n = n0 + wn + ni * 16 + l15;
                out[(size_t)m * D_MODEL + n] = acc[mi][ni][i];
            }
}

extern "C" void kernel_launch(void* const* d_in, const int* in_sizes, int n_in,
                              void* d_out, int out_size, void* d_ws, size_t ws_size,
                              hipStream_t stream) {
    const float* x  = (const float*)d_in[0];
    const float* Wq = (const float*)d_in[1];
    const float* Wk = (const float*)d_in[2];
    const float* Wv = (const float*)d_in[3];
    const float* Wo = (const float*)d_in[4];
    float* out = (float*)d_out;

    u16* ws = (u16*)d_ws;
    const size_t M1 = 1048576;
    u16* xb    = ws;            // 4M
    u16* wqkv  = ws + 4 * M1;   // 3M  (Wq|Wk|Wv rows stacked)
    u16* wob   = ws + 7 * M1;   // 1M
    u16* qb    = ws + 8 * M1;   // 4M (B,H,S,DK), scaled by 1/8
    u16* kb    = ws + 12 * M1;  // 4M (B,H,S,DK)
    u16* vtb   = ws + 16 * M1;  // 4M (B,H,DK,S)
    u16* attnb = ws + 20 * M1;  // 4M (B,S,D)

    convert_bf16<<<dim3(4096), dim3(256), 0, stream>>>(x, Wq, Wk, Wv, Wo, xb, wqkv, wob);
    gemm_qkv<<<dim3(MROWS / 128, 3072 / 128), dim3(256), 0, stream>>>(xb, wqkv, qb, kb, vtb);
    attn_mfma<<<dim3(SEQ / 64, NHEAD, NBATCH), dim3(256), 0, stream>>>(qb, kb, vtb, attnb);
    gemm_proj<<<dim3(MROWS / 128, D_MODEL / 128), dim3(256), 0, stream>>>(attnb, wob, out);
}